// Round 3
// baseline (137.167 us; speedup 1.0000x reference)
//
#include <hip/hip_runtime.h>
#include <hip/hip_bf16.h>
#include <math.h>

#define B_  8
#define C_  128
#define CH_ 64
#define LX_ 128
#define LY_ 1024

typedef __attribute__((ext_vector_type(8))) _Float16 half8;
typedef __attribute__((ext_vector_type(4))) _Float16 half4;
typedef __attribute__((ext_vector_type(8))) unsigned short ushort8;
typedef __attribute__((ext_vector_type(4))) float f32x4;

// ---------------- K0: wdTh[kh][c] = (fp16) W_down[c][kh]  (8192 elems) ------------
__global__ __launch_bounds__(256) void k0_prep(const float* __restrict__ wd,
                                               _Float16* __restrict__ wdTh) {
    int u = blockIdx.x * 256 + threadIdx.x;
    int kh = u >> 7, c = u & 127;
    wdTh[u] = (_Float16)wd[c * CH_ + kh];
}

// ---------------- K1: att = x^T @ W + b  (+ zero Hx/Hy) ---------------------------
__global__ __launch_bounds__(128) void k1_att(
    const float* __restrict__ x, const float* __restrict__ y,
    const float* __restrict__ Wd, const float* __restrict__ bd,
    const float* __restrict__ Wp, const float* __restrict__ bp,
    float* __restrict__ datt, float* __restrict__ patt,
    float2* __restrict__ zero_region)
{
    // fold the Hx/Hy zeroing in: 2304 blocks * 128 thr * 1 float2 = 589824 floats
    zero_region[blockIdx.x * 128 + threadIdx.x] = (float2){0.f, 0.f};

    const int blk = blockIdx.x;
    const float* src; const float* W; const float* bias; float* dst; int L;
    int b, l0;
    if (blk < 256) {
        int row0 = blk * 4; b = row0 >> 7; l0 = row0 & 127;
        src = x; W = Wd; bias = bd; dst = datt; L = LX_;
    } else {
        int row0 = (blk - 256) * 4; b = row0 >> 10; l0 = row0 & 1023;
        src = y; W = Wp; bias = bp; dst = patt; L = LY_;
    }
    __shared__ float col[4][128];
    const int t = threadIdx.x;
    {
        const float* sp = src + ((long)b * C_ + t) * L + l0;
        float4 v = *(const float4*)sp;
        col[0][t] = v.x; col[1][t] = v.y; col[2][t] = v.z; col[3][t] = v.w;
    }
    __syncthreads();
    float acc0 = bias[t], acc1 = acc0, acc2 = acc0, acc3 = acc0;
    #pragma unroll 8
    for (int c = 0; c < 128; ++c) {
        float w = W[c * 128 + t];
        float s0 = col[0][c], s1 = col[1][c], s2 = col[2][c], s3 = col[3][c];
        acc0 = fmaf(s0, w, acc0); acc1 = fmaf(s1, w, acc1);
        acc2 = fmaf(s2, w, acc2); acc3 = fmaf(s3, w, acc3);
    }
    float* dp = dst + ((long)b * L + l0) * C_ + t;
    dp[0] = acc0; dp[C_] = acc1; dp[2 * C_] = acc2; dp[3 * C_] = acc3;
}

// ---------------- K2: fp16 MFMA pair-GEMM + fused axis reductions -----------------
// block = (b, 32 lx, 32 ly), 256 thr (4 waves), wave w owns lx rows [8w, 8w+8).
// LDS 34 KB -> 4 blocks/CU. s = relu(d+p) built with v_pk_add/max_f16, zero cvt.
__global__ __launch_bounds__(256, 4) void k2_main(
    const float* __restrict__ datt, const float* __restrict__ patt,
    const _Float16* __restrict__ wdTh, const float* __restrict__ bdown,
    float* __restrict__ Hx, float* __restrict__ Hy)
{
    const int lyblk = blockIdx.x;   // 0..31
    const int lxblk = blockIdx.y;   // 0..3
    const int b     = blockIdx.z;   // 0..7
    const int t     = threadIdx.x;
    const int w     = t >> 6;
    const int g     = (t >> 4) & 3;
    const int q     = t & 15;

    __shared__ _Float16 dTh[32][136];
    __shared__ _Float16 pTh[32][136];
    __shared__ __align__(16) char ubuf[17408];       // union: wt | (compH, protH)
    _Float16 (*wt)[136]  = (_Float16(*)[136])ubuf;   // [64][136] fp16 = 17408 B
    float (*compH)[66]   = (float(*)[66])ubuf;       // [32][66] f32 = 8448 B
    float (*protH)[66]   = (float(*)[66])(ubuf + 8448);

    // ---- stage tiles (f32 -> fp16) and pre-transposed W_down (fp16) ----
    {
        const float* dsrc = datt + ((long)b * LX_ + lxblk * 32) * C_;
        const float* psrc = patt + ((long)b * LY_ + lyblk * 32) * C_;
        #pragma unroll
        for (int i = 0; i < 4; ++i) {
            int u4 = t + i * 256;                    // 1024 float4 groups
            int r = u4 >> 5, c = (u4 & 31) * 4;
            float4 dv = *(const float4*)(dsrc + u4 * 4);
            float4 pv = *(const float4*)(psrc + u4 * 4);
            half4 dh = {(_Float16)dv.x, (_Float16)dv.y, (_Float16)dv.z, (_Float16)dv.w};
            half4 ph = {(_Float16)pv.x, (_Float16)pv.y, (_Float16)pv.z, (_Float16)pv.w};
            *(half4*)&dTh[r][c] = dh;
            *(half4*)&pTh[r][c] = ph;
        }
        #pragma unroll
        for (int i = 0; i < 4; ++i) {
            int idx = t + i * 256;                   // 1024 groups of 8 halves
            int r = idx >> 4, c = (idx & 15) * 8;
            *(ushort8*)&wt[r][c] = ((const ushort8*)wdTh)[idx];
        }
    }
    __syncthreads();

    // ---- B-fragments from wt: lane holds B[k=kt*32+g*8+j][n=nt*16+q] ----
    half8 bf[4][4];
    #pragma unroll
    for (int kt = 0; kt < 4; ++kt)
        #pragma unroll
        for (int nt = 0; nt < 4; ++nt)
            bf[kt][nt] = *(const half8*)&wt[nt * 16 + q][kt * 32 + g * 8];
    float bdr[4];
    #pragma unroll
    for (int nt = 0; nt < 4; ++nt) bdr[nt] = bdown[nt * 16 + q];
    __syncthreads();

    // ---- zero block partials (aliases wt) ----
    for (int u = t; u < 4224; u += 256) ((float*)ubuf)[u] = 0.f;
    __syncthreads();

    const half8 hz = {};
    #pragma unroll 1
    for (int lyg = 0; lyg < 2; ++lyg) {
        half8 pv[4];
        #pragma unroll
        for (int kt = 0; kt < 4; ++kt)
            pv[kt] = *(const half8*)&pTh[lyg * 16 + q][kt * 32 + g * 8];
        float hy[4][4];
        #pragma unroll
        for (int nt = 0; nt < 4; ++nt)
            #pragma unroll
            for (int r = 0; r < 4; ++r) hy[nt][r] = 0.f;

        #pragma unroll 1
        for (int lxr = 0; lxr < 8; ++lxr) {
            const int lxi = w * 8 + lxr;
            f32x4 acc[4];
            #pragma unroll
            for (int nt = 0; nt < 4; ++nt)
                acc[nt] = (f32x4){bdr[nt], bdr[nt], bdr[nt], bdr[nt]};
            #pragma unroll
            for (int kt = 0; kt < 4; ++kt) {
                half8 dv = *(const half8*)&dTh[lxi][kt * 32 + g * 8];  // broadcast
                half8 s  = __builtin_elementwise_max(dv + pv[kt], hz); // pk_add+pk_max
                #pragma unroll
                for (int nt = 0; nt < 4; ++nt)
                    acc[nt] = __builtin_amdgcn_mfma_f32_16x16x32_f16(
                        s, bf[kt][nt], acc[nt], 0, 0, 0);
            }
            // D-layout: col(kh)=q+16nt, row(ly)=lyg*16+4g+reg
            float cp0 = 0.f, cp1 = 0.f, cp2 = 0.f, cp3 = 0.f;
            #pragma unroll
            for (int nt = 0; nt < 4; ++nt) {
                float h0 = fmaxf(acc[nt][0], 0.f);
                float h1 = fmaxf(acc[nt][1], 0.f);
                float h2 = fmaxf(acc[nt][2], 0.f);
                float h3 = fmaxf(acc[nt][3], 0.f);
                hy[nt][0] += h0; hy[nt][1] += h1;
                hy[nt][2] += h2; hy[nt][3] += h3;
                float s2 = (h0 + h1) + (h2 + h3);
                s2 += __shfl_xor(s2, 16);
                s2 += __shfl_xor(s2, 32);
                if      (nt == 0) cp0 = s2;
                else if (nt == 1) cp1 = s2;
                else if (nt == 2) cp2 = s2;
                else              cp3 = s2;
            }
            float cpv = (g == 0) ? cp0 : (g == 1) ? cp1 : (g == 2) ? cp2 : cp3;
            atomicAdd(&compH[lxi][(g << 4) + q], cpv);
        }
        #pragma unroll
        for (int nt = 0; nt < 4; ++nt)
            #pragma unroll
            for (int r = 0; r < 4; ++r)
                atomicAdd(&protH[lyg * 16 + (g << 2) + r][nt * 16 + q], hy[nt][r]);
    }
    __syncthreads();

    // ---- block partials -> global atomics ----
    for (int u = t; u < 2048; u += 256) {
        int r = u >> 6, c = u & 63;
        atomicAdd(&Hx[((long)(b * LX_) + lxblk * 32 + r) * 64 + c], compH[r][c]);
        atomicAdd(&Hy[((long)(b * LY_) + lyblk * 32 + r) * 64 + c], protH[r][c]);
    }
}

// ---------------- K3: (H*invN) @ W_up + b_up -> gate -> transpose -> out ----------
// merged drug+prot: blockIdx.x < 4 -> drug; c-tiled for parallelism (1152 blocks)
__global__ __launch_bounds__(256) void k3_gate(
    const float* __restrict__ Hx, const float* __restrict__ Hy,
    const float* __restrict__ wup, const float* __restrict__ bup,
    const float* __restrict__ x, const float* __restrict__ y,
    float* __restrict__ out)
{
    const int b  = blockIdx.z;
    const int c0 = blockIdx.y * 32;
    const float* H; const float* xin; float* outp; int L; float invN; int l0;
    if (blockIdx.x < 4) {
        H = Hx; xin = x; outp = out; L = LX_; invN = 1.f / 1024.f;
        l0 = blockIdx.x * 32;
    } else {
        H = Hy; xin = y; outp = out + (long)B_ * C_ * LX_; L = LY_; invN = 1.f / 128.f;
        l0 = (blockIdx.x - 4) * 32;
    }
    const int t = threadIdx.x;
    __shared__ float Ht[32][68];
    __shared__ float Wt[64][36];
    __shared__ float gg[32][36];
    for (int u = t; u < 32 * 64; u += 256)
        Ht[u >> 6][u & 63] = H[((long)b * L + l0 + (u >> 6)) * 64 + (u & 63)];
    for (int u = t; u < 64 * 32; u += 256)
        Wt[u >> 5][u & 31] = wup[(u >> 5) * C_ + c0 + (u & 31)];
    __syncthreads();

    const int l = t >> 3, cg = (t & 7) * 4;
    float a0 = 0.f, a1 = 0.f, a2 = 0.f, a3 = 0.f;
    #pragma unroll 8
    for (int k = 0; k < 64; ++k) {
        float hv = Ht[l][k];
        float4 wv = *(const float4*)&Wt[k][cg];
        a0 = fmaf(hv, wv.x, a0); a1 = fmaf(hv, wv.y, a1);
        a2 = fmaf(hv, wv.z, a2); a3 = fmaf(hv, wv.w, a3);
    }
    float av[4] = {a0, a1, a2, a3};
    #pragma unroll
    for (int i = 0; i < 4; ++i) {
        float v = fmaf(av[i], invN, bup[c0 + cg + i]);
        float sg = 1.f / (1.f + expf(-v));
        gg[l][cg + i] = sg * tanhf(v);
    }
    __syncthreads();
    for (int u = t; u < 1024; u += 256) {
        int c = u >> 5, li = u & 31;
        long idx = ((long)b * C_ + c0 + c) * L + l0 + li;
        outp[idx] = xin[idx] * (0.5f + gg[li][c]);
    }
}

extern "C" void kernel_launch(void* const* d_in, const int* in_sizes, int n_in,
                              void* d_out, int out_size, void* d_ws, size_t ws_size,
                              hipStream_t stream) {
    (void)in_sizes; (void)n_in; (void)out_size; (void)ws_size;
    const float* x     = (const float*)d_in[0];
    const float* y     = (const float*)d_in[1];
    const float* Wdrug = (const float*)d_in[2];
    const float* bdrug = (const float*)d_in[3];
    const float* Wprot = (const float*)d_in[4];
    const float* bprot = (const float*)d_in[5];
    const float* Wdown = (const float*)d_in[6];
    const float* bdown = (const float*)d_in[7];
    const float* Wup   = (const float*)d_in[8];
    const float* bup   = (const float*)d_in[9];
    float* out = (float*)d_out;
    float* ws  = (float*)d_ws;

    float* datt = ws;                        // B*LX*C  = 131072
    float* patt = ws + 131072;               // B*LY*C  = 1048576
    float* Hx   = ws + 1179648;              // B*LX*64 = 65536
    float* Hy   = ws + 1245184;              // B*LY*64 = 524288
    _Float16* wdTh = (_Float16*)(ws + 1769472);  // 8192 halves

    hipLaunchKernelGGL(k0_prep, dim3(32), dim3(256), 0, stream, Wdown, wdTh);
    hipLaunchKernelGGL(k1_att, dim3(2304), dim3(128), 0, stream,
                       x, y, Wdrug, bdrug, Wprot, bprot, datt, patt, (float2*)Hx);
    hipLaunchKernelGGL(k2_main, dim3(32, 4, 8), dim3(256), 0, stream,
                       datt, patt, wdTh, bdown, Hx, Hy);
    hipLaunchKernelGGL(k3_gate, dim3(36, 4, 8), dim3(256), 0, stream,
                       Hx, Hy, Wup, bup, x, y, out);
}